// Round 13
// baseline (172.313 us; speedup 1.0000x reference)
//
#include <hip/hip_runtime.h>
#include <cstddef>
#include <cstdint>

// Problem constants
#define Bsz  2
#define Ssz  2048
#define Dsz  768
#define Hsz  12
#define DHsz 64
#define Msz  4096   // B*S
#define N3sz 2304   // 3*D
#define Kdim 768

typedef short bf16x8 __attribute__((ext_vector_type(8)));
typedef short bf16x4 __attribute__((ext_vector_type(4)));
typedef float f32x4  __attribute__((ext_vector_type(4)));
typedef const __attribute__((address_space(1))) void gvoid;
typedef __attribute__((address_space(3))) void lvoid;

// fp32 -> bf16 bits, round-to-nearest-even
static __device__ __forceinline__ unsigned short f2bf(float f) {
    unsigned int u = __builtin_bit_cast(unsigned int, f);
    u += 0x7FFFu + ((u >> 16) & 1u);
    return (unsigned short)(u >> 16);
}
// pack two fp32 -> bf16x2 dword
static __device__ __forceinline__ unsigned int pk2bf(float a, float b) {
    return (unsigned int)f2bf(a) | ((unsigned int)f2bf(b) << 16);
}

// ---------------------------------------------------------------------------
// Fused prep: blocks [0,1536) cast x; [1536,1968) transpose Wqkv;
// [1968,2112) transpose Wproj. Block 0 also zeroes the attn work counter.
// ---------------------------------------------------------------------------
static __device__ __forceinline__ void transpose_body(
    const float* __restrict__ W, unsigned short* __restrict__ Wt, int N,
    int bx, int by, int tid, float (*T)[65])
{
    const int n0 = bx << 6;
    const int k0 = by << 6;
#pragma unroll
    for (int p = 0; p < 4; ++p) {
        const int idx = p * 256 + tid;
        const int r  = idx >> 4;
        const int c4 = (idx & 15) << 2;
        const float4 v = *(const float4*)&W[(size_t)(k0 + r) * N + n0 + c4];
        T[r][c4 + 0] = v.x; T[r][c4 + 1] = v.y;
        T[r][c4 + 2] = v.z; T[r][c4 + 3] = v.w;
    }
    __syncthreads();
#pragma unroll
    for (int p = 0; p < 4; ++p) {
        const int idx = p * 256 + tid;
        const int r  = idx >> 4;
        const int c4 = (idx & 15) << 2;
        ushort4 o;
        o.x = f2bf(T[c4 + 0][r]); o.y = f2bf(T[c4 + 1][r]);
        o.z = f2bf(T[c4 + 2][r]); o.w = f2bf(T[c4 + 3][r]);
        *(ushort4*)&Wt[(size_t)(n0 + r) * Kdim + k0 + c4] = o;
    }
}

__global__ __launch_bounds__(256) void prep_kernel(
    const float* __restrict__ X, unsigned short* __restrict__ Xb,
    const float* __restrict__ Wqkv, unsigned short* __restrict__ Wqkvt,
    const float* __restrict__ Wproj, unsigned short* __restrict__ Wprojt,
    unsigned int* __restrict__ counter)
{
    __shared__ float T[64][65];
    const int bid = blockIdx.x;
    const int tid = threadIdx.x;
    if (bid == 0 && tid == 0) *counter = 0;   // attn work-queue head
    if (bid < 1536) {
        const size_t i = ((size_t)bid * 256 + tid) * 8;
        const float4 a = *(const float4*)&X[i];
        const float4 b = *(const float4*)&X[i + 4];
        ushort4 lo, hi;
        lo.x = f2bf(a.x); lo.y = f2bf(a.y); lo.z = f2bf(a.z); lo.w = f2bf(a.w);
        hi.x = f2bf(b.x); hi.y = f2bf(b.y); hi.z = f2bf(b.z); hi.w = f2bf(b.w);
        *(ushort4*)&Xb[i] = lo;
        *(ushort4*)&Xb[i + 4] = hi;
    } else if (bid < 1536 + 432) {
        const int idx = bid - 1536;               // 36 n-tiles x 12 k-tiles
        transpose_body(Wqkv, Wqkvt, N3sz, idx % 36, idx / 36, tid, T);
    } else {
        const int idx = bid - 1968;               // 12 x 12
        transpose_body(Wproj, Wprojt, Dsz, idx % 12, idx / 12, tid, T);
    }
}

// ---------------------------------------------------------------------------
// QKV GEMM (unchanged from R12): 128x128 tile, BK=64, transposed-C MFMA,
// Q/K coalesced row scatter, V written transposed Vt[bh][d][s].
// ---------------------------------------------------------------------------
__global__ __launch_bounds__(256) void qkv_gemm_kernel(
    const unsigned short* __restrict__ A,
    const unsigned short* __restrict__ Bt,
    const float* __restrict__ bias,
    unsigned short* __restrict__ Qo, unsigned short* __restrict__ Ko,
    unsigned short* __restrict__ Vt)
{
    __shared__ unsigned short smem[128 * 136];
    unsigned short* Als = smem;
    unsigned short* Bls = smem + 8192;

    const int tid  = threadIdx.x;
    const int w    = tid >> 6;
    const int lane = tid & 63;
    const int quad = lane >> 4;
    const int t16  = lane & 15;
    const int wm   = w & 1;
    const int wn   = w >> 1;
    const int m0   = blockIdx.y << 7;
    const int n0   = blockIdx.x << 7;

    const int lrow = lane >> 3;
    const int lch  = lane & 7;
    const unsigned short* Ag = A  + (size_t)(m0 + lrow) * Kdim + ((lch ^ lrow) << 3);
    const unsigned short* Bg = Bt + (size_t)(n0 + lrow) * Kdim + ((lch ^ lrow) << 3);

    f32x4 acc[4][4];
#pragma unroll
    for (int mt = 0; mt < 4; ++mt)
#pragma unroll
        for (int nt = 0; nt < 4; ++nt) acc[mt][nt] = (f32x4)(0.f);

    for (int k0 = 0; k0 < Kdim; k0 += 64) {
        __syncthreads();
#pragma unroll
        for (int t = 0; t < 4; ++t) {
            const int i = (w << 2) + t;
            __builtin_amdgcn_global_load_lds(
                (gvoid*)(Ag + (size_t)(i << 3) * Kdim + k0),
                (lvoid*)(Als + (i << 9)), 16, 0, 0);
            __builtin_amdgcn_global_load_lds(
                (gvoid*)(Bg + (size_t)(i << 3) * Kdim + k0),
                (lvoid*)(Bls + (i << 9)), 16, 0, 0);
        }
        __syncthreads();

#pragma unroll
        for (int ks = 0; ks < 2; ++ks) {
            const int sl = (((ks << 2) + quad) ^ (t16 & 7)) << 3;
            bf16x8 af[4], bfr[4];
#pragma unroll
            for (int mt = 0; mt < 4; ++mt)
                af[mt] = *(const bf16x8*)&Als[(((wm << 6) + (mt << 4) + t16) << 6) + sl];
#pragma unroll
            for (int nt = 0; nt < 4; ++nt)
                bfr[nt] = *(const bf16x8*)&Bls[(((wn << 6) + (nt << 4) + t16) << 6) + sl];
#pragma unroll
            for (int mt = 0; mt < 4; ++mt)
#pragma unroll
                for (int nt = 0; nt < 4; ++nt)
                    acc[mt][nt] = __builtin_amdgcn_mfma_f32_16x16x32_bf16(
                        bfr[nt], af[mt], acc[mt][nt], 0, 0, 0);
        }
    }

    __syncthreads();
    {
        const int seg = n0 / Dsz;
        const float sc = (seg == 0) ? 0.18033688f : 1.0f;   // 0.125*log2(e)
#pragma unroll
        for (int nt = 0; nt < 4; ++nt) {
            const int nl = (wn << 6) + (nt << 4) + (quad << 2);
            const float4 bn = *(const float4*)&bias[n0 + nl];
#pragma unroll
            for (int mt = 0; mt < 4; ++mt) {
                const int ml = (wm << 6) + (mt << 4) + t16;
                uint2 o;
                o.x = pk2bf((acc[mt][nt][0] + bn.x) * sc,
                            (acc[mt][nt][1] + bn.y) * sc);
                o.y = pk2bf((acc[mt][nt][2] + bn.z) * sc,
                            (acc[mt][nt][3] + bn.w) * sc);
                *(uint2*)&smem[ml * 136 + nl] = o;
            }
        }
        __syncthreads();

        const int h0 = (n0 % Dsz) >> 6;
        const int bI = m0 >> 11;
        const int s0 = m0 & 2047;
        if (seg < 2) {
            unsigned short* dst0 = (seg == 0) ? Qo : Ko;
            const int chunk = tid & 7;
#pragma unroll
            for (int p = 0; p < 8; ++p) {
                const int unit = p * 32 + (tid >> 3);
                const int ml = unit >> 1;
                const int hc = unit & 1;
                const int s  = s0 + ml;
                const uint4 v = *(const uint4*)&smem[ml * 136 + (hc << 6) + (chunk << 3)];
                *(uint4*)&dst0[(((size_t)bI * Hsz + h0 + hc) * Ssz + s) * DHsz
                               + (chunk << 3)] = v;
            }
        } else {
            const int nrow = tid >> 1;
            const int mh   = tid & 1;
            const int d    = nrow & 63;
            const int hc   = nrow >> 6;
            unsigned short* dst = Vt
                + ((size_t)(bI * Hsz + h0 + hc) * DHsz + d) * Ssz + s0 + (mh << 6);
#pragma unroll
            for (int c = 0; c < 4; ++c) {
                unsigned int dw[8];
#pragma unroll
                for (int k = 0; k < 8; ++k) {
                    const int j = c * 16 + 2 * k;
                    dw[k] = (unsigned int)smem[((mh << 6) + j) * 136 + nrow]
                          | ((unsigned int)smem[((mh << 6) + j + 1) * 136 + nrow] << 16);
                }
                *(uint4*)&dst[c * 16]     = make_uint4(dw[0], dw[1], dw[2], dw[3]);
                *(uint4*)&dst[c * 16 + 8] = make_uint4(dw[4], dw[5], dw[6], dw[7]);
            }
        }
    }
}

// ---------------------------------------------------------------------------
// Proj GEMM: 64x64 tile (unchanged).
// ---------------------------------------------------------------------------
__global__ __launch_bounds__(256) void proj_gemm_kernel(
    const unsigned short* __restrict__ A,
    const unsigned short* __restrict__ Bt,
    const float* __restrict__ bias, float* __restrict__ Out)
{
    __shared__ float smemf[64 * 68];
    unsigned short* Als = (unsigned short*)smemf;
    unsigned short* Bls = Als + 4096;

    const int tid  = threadIdx.x;
    const int w    = tid >> 6;
    const int lane = tid & 63;
    const int quad = lane >> 4;
    const int t16  = lane & 15;
    const int wm   = w & 1;
    const int wn   = w >> 1;
    const int m0   = blockIdx.y << 6;
    const int n0   = blockIdx.x << 6;

    const int lrow = lane >> 3;
    const int lch  = lane & 7;
    const unsigned short* Ag = A  + (size_t)(m0 + lrow) * Kdim + ((lch ^ lrow) << 3);
    const unsigned short* Bg = Bt + (size_t)(n0 + lrow) * Kdim + ((lch ^ lrow) << 3);

    f32x4 acc[2][2];
#pragma unroll
    for (int mt = 0; mt < 2; ++mt)
#pragma unroll
        for (int nt = 0; nt < 2; ++nt) acc[mt][nt] = (f32x4)(0.f);

    for (int k0 = 0; k0 < Kdim; k0 += 64) {
        __syncthreads();
#pragma unroll
        for (int t = 0; t < 2; ++t) {
            const int i = (w << 1) + t;
            __builtin_amdgcn_global_load_lds(
                (gvoid*)(Ag + (size_t)(i << 3) * Kdim + k0),
                (lvoid*)(Als + (i << 9)), 16, 0, 0);
            __builtin_amdgcn_global_load_lds(
                (gvoid*)(Bg + (size_t)(i << 3) * Kdim + k0),
                (lvoid*)(Bls + (i << 9)), 16, 0, 0);
        }
        __syncthreads();

#pragma unroll
        for (int ks = 0; ks < 2; ++ks) {
            const int sl = (((ks << 2) + quad) ^ (t16 & 7)) << 3;
            bf16x8 af[2], bfr[2];
#pragma unroll
            for (int mt = 0; mt < 2; ++mt)
                af[mt] = *(const bf16x8*)&Als[(((wm << 5) + (mt << 4) + t16) << 6) + sl];
#pragma unroll
            for (int nt = 0; nt < 2; ++nt)
                bfr[nt] = *(const bf16x8*)&Bls[(((wn << 5) + (nt << 4) + t16) << 6) + sl];
#pragma unroll
            for (int mt = 0; mt < 2; ++mt)
#pragma unroll
                for (int nt = 0; nt < 2; ++nt)
                    acc[mt][nt] = __builtin_amdgcn_mfma_f32_16x16x32_bf16(
                        bfr[nt], af[mt], acc[mt][nt], 0, 0, 0);
        }
    }

    __syncthreads();
#pragma unroll
    for (int nt = 0; nt < 2; ++nt) {
        const int nl = (wn << 5) + (nt << 4) + (quad << 2);
        const float4 bn = *(const float4*)&bias[n0 + nl];
#pragma unroll
        for (int mt = 0; mt < 2; ++mt) {
            const int ml = (wm << 5) + (mt << 4) + t16;
            float4 o;
            o.x = acc[mt][nt][0] + bn.x;
            o.y = acc[mt][nt][1] + bn.y;
            o.z = acc[mt][nt][2] + bn.z;
            o.w = acc[mt][nt][3] + bn.w;
            *(float4*)&smemf[ml * 68 + nl] = o;
        }
    }
    __syncthreads();
    {
        const int c16 = tid & 15;
#pragma unroll
        for (int p = 0; p < 4; ++p) {
            const int ml = p * 16 + (tid >> 4);
            const float4 v = *(const float4*)&smemf[ml * 68 + (c16 << 2)];
            *(float4*)&Out[(size_t)(m0 + ml) * Dsz + n0 + (c16 << 2)] = v;
        }
    }
}

// ---------------------------------------------------------------------------
// MFMA flash attention v7: dynamic work queue. 512 blocks pop 768 (qt,bh)
// items in descending-cost order via atomicAdd (LPT greedy: makespan ~= avg
// + one item, robust to the undefined dispatch->CU mapping). Per-item body
// identical to v6 (reg-resident PV, no-max softmax, K/V dbuf, Vt input).
// ---------------------------------------------------------------------------
__global__ __launch_bounds__(256) void attn_mfma_kernel(
    const unsigned short* __restrict__ Q, const unsigned short* __restrict__ K,
    const unsigned short* __restrict__ Vt, unsigned short* __restrict__ Aout,
    unsigned int* __restrict__ counter)
{
    __shared__ unsigned short Kls[2][64 * 72];   // [buf][kv][d]
    __shared__ unsigned short Vls[2][64 * 72];   // [buf][d][kv]
    __shared__ unsigned int s_item;

    const int tid  = threadIdx.x;
    const int w    = tid >> 6;
    const int lane = tid & 63;
    const int quad = lane >> 4;
    const int t16  = lane & 15;

    const int row_a = tid >> 3;          // 0..31 (+32 second item)
    const int ch_a  = tid & 7;           // 16B chunk

    for (;;) {
        __syncthreads();                 // prior item fully done (LDS reusable)
        if (tid == 0) s_item = atomicAdd(counter, 1u);
        __syncthreads();
        const unsigned int u = s_item;
        if (u >= 768u) break;

        const int qt   = 31 - (int)(u / 24);   // descending cost
        const int bh   = (int)(u % 24);
        const int q0   = qt << 6;
        const int bIdx = bh / Hsz;
        const int h    = bh % Hsz;

        const size_t base  = (size_t)bh * Ssz * DHsz;    // K/Q base
        const size_t vbase = (size_t)bh * DHsz * Ssz;    // Vt base

        // Q fragment (B-operand for S^T)
        bf16x8 qf[2];
#pragma unroll
        for (int s = 0; s < 2; ++s)
            qf[s] = *(const bf16x8*)&Q[base + (size_t)(q0 + w * 16 + t16) * DHsz
                                       + s * 32 + quad * 8];

        f32x4 O[4];
        float l_ps = 0.f;
#pragma unroll
        for (int dt = 0; dt < 4; ++dt) O[dt] = (f32x4)(0.f);

        // stage tile 0
        {
            const unsigned short* Kb = K + base;
            const unsigned short* Vb = Vt + vbase;
            const uint4 k0a = *(const uint4*)&Kb[(size_t)row_a * DHsz + ch_a * 8];
            const uint4 k0b = *(const uint4*)&Kb[(size_t)(row_a + 32) * DHsz + ch_a * 8];
            const uint4 v0a = *(const uint4*)&Vb[(size_t)row_a * Ssz + ch_a * 8];
            const uint4 v0b = *(const uint4*)&Vb[(size_t)(row_a + 32) * Ssz + ch_a * 8];
            *(uint4*)&Kls[0][row_a * 72 + ch_a * 8] = k0a;
            *(uint4*)&Kls[0][(row_a + 32) * 72 + ch_a * 8] = k0b;
            *(uint4*)&Vls[0][row_a * 72 + ch_a * 8] = v0a;
            *(uint4*)&Vls[0][(row_a + 32) * 72 + ch_a * 8] = v0b;
        }
        __syncthreads();

        for (int kt = 0; kt <= qt; ++kt) {
            const int cur = kt & 1;
            const int nxt = cur ^ 1;

            uint4 kr0, kr1, vr0, vr1;
            if (kt < qt) {
                const unsigned short* Kb = K + base + (size_t)((kt + 1) << 6) * DHsz;
                const unsigned short* Vb = Vt + vbase + ((kt + 1) << 6);
                kr0 = *(const uint4*)&Kb[(size_t)row_a * DHsz + ch_a * 8];
                kr1 = *(const uint4*)&Kb[(size_t)(row_a + 32) * DHsz + ch_a * 8];
                vr0 = *(const uint4*)&Vb[(size_t)row_a * Ssz + ch_a * 8];
                vr1 = *(const uint4*)&Vb[(size_t)(row_a + 32) * Ssz + ch_a * 8];
            }

            // S^T = K Q^T
            f32x4 St[4];
#pragma unroll
            for (int kb = 0; kb < 4; ++kb) St[kb] = (f32x4)(0.f);
#pragma unroll
            for (int s = 0; s < 2; ++s)
#pragma unroll
                for (int kb = 0; kb < 4; ++kb) {
                    const bf16x8 kf = *(const bf16x8*)&Kls[cur][(kb * 16 + t16) * 72
                                                               + s * 32 + quad * 8];
                    St[kb] = __builtin_amdgcn_mfma_f32_16x16x32_bf16(
                        kf, qf[s], St[kb], 0, 0, 0);
                }

            if (kt == qt) {
                const int qrel = w * 16 + t16;
#pragma unroll
                for (int kb = 0; kb < 4; ++kb) {
                    const int kvb = kb * 16 + quad * 4;
#pragma unroll
                    for (int r = 0; r < 4; ++r)
                        if (kvb + r > qrel) St[kb][r] = -1e30f;
                }
            }

            // no-max softmax; P stays in registers as K=16 B-operand
#pragma unroll
            for (int kb = 0; kb < 4; ++kb) {
                const float p0 = exp2f(St[kb][0]);
                const float p1 = exp2f(St[kb][1]);
                const float p2 = exp2f(St[kb][2]);
                const float p3 = exp2f(St[kb][3]);
                l_ps += (p0 + p1) + (p2 + p3);
                uint2 pk;
                pk.x = pk2bf(p0, p1);
                pk.y = pk2bf(p2, p3);
                const bf16x4 pf = __builtin_bit_cast(bf16x4, pk);
#pragma unroll
                for (int dt = 0; dt < 4; ++dt) {
                    const bf16x4 vf = *(const bf16x4*)&Vls[cur][(dt * 16 + t16) * 72
                                                                + kb * 16 + quad * 4];
                    O[dt] = __builtin_amdgcn_mfma_f32_16x16x16bf16_1k(vf, pf, O[dt], 0, 0, 0);
                }
            }

            if (kt < qt) {
                *(uint4*)&Kls[nxt][row_a * 72 + ch_a * 8] = kr0;
                *(uint4*)&Kls[nxt][(row_a + 32) * 72 + ch_a * 8] = kr1;
                *(uint4*)&Vls[nxt][row_a * 72 + ch_a * 8] = vr0;
                *(uint4*)&Vls[nxt][(row_a + 32) * 72 + ch_a * 8] = vr1;
                __syncthreads();
            }
        }

        l_ps += __shfl_xor(l_ps, 16);
        l_ps += __shfl_xor(l_ps, 32);
        {
            const float inv = 1.0f / l_ps;
            const int q = q0 + w * 16 + t16;
            unsigned short* dst = Aout + ((size_t)bIdx * Ssz + q) * Dsz + (h << 6);
#pragma unroll
            for (int dt = 0; dt < 4; ++dt) {
                uint2 o;
                o.x = pk2bf(O[dt][0] * inv, O[dt][1] * inv);
                o.y = pk2bf(O[dt][2] * inv, O[dt][3] * inv);
                *(uint2*)&dst[dt * 16 + quad * 4] = o;
            }
        }
    }
}

// ---------------------------------------------------------------------------
extern "C" void kernel_launch(void* const* d_in, const int* in_sizes, int n_in,
                              void* d_out, int out_size, void* d_ws, size_t ws_size,
                              hipStream_t stream) {
    const float* x        = (const float*)d_in[0];
    const float* c_attn_w = (const float*)d_in[2];
    const float* c_attn_b = (const float*)d_in[3];
    const float* c_proj_w = (const float*)d_in[4];
    const float* c_proj_b = (const float*)d_in[5];
    float* out = (float*)d_out;

    const size_t T = (size_t)Msz * Dsz;           // 3145728
    unsigned short* xb     = (unsigned short*)d_ws;
    unsigned short* Wqkvt  = xb + T;
    unsigned short* Wprojt = Wqkvt + (size_t)N3sz * Kdim;
    unsigned short* Qw     = Wprojt + (size_t)Dsz * Kdim;
    unsigned short* Kw     = Qw + T;
    unsigned short* Vw     = Kw + T;               // Vt layout [bh][d][s]
    unsigned short* Ab     = Vw + T;
    unsigned int*   cnt    = (unsigned int*)(Ab + T);

    prep_kernel<<<2112, 256, 0, stream>>>(x, xb, c_attn_w, Wqkvt,
                                          c_proj_w, Wprojt, cnt);
    qkv_gemm_kernel<<<dim3(N3sz / 128, Msz / 128), 256, 0, stream>>>(
        xb, Wqkvt, c_attn_b, Qw, Kw, Vw);
    attn_mfma_kernel<<<512, 256, 0, stream>>>(Qw, Kw, Vw, Ab, cnt);
    proj_gemm_kernel<<<dim3(Dsz / 64, Msz / 64), 256, 0, stream>>>(
        Ab, Wprojt, c_proj_b, out);
}

// Round 14
// 162.367 us; speedup vs baseline: 1.0613x; 1.0613x over previous
//
#include <hip/hip_runtime.h>
#include <cstddef>
#include <cstdint>

// Problem constants
#define Bsz  2
#define Ssz  2048
#define Dsz  768
#define Hsz  12
#define DHsz 64
#define Msz  4096   // B*S
#define N3sz 2304   // 3*D
#define Kdim 768

typedef short bf16x8 __attribute__((ext_vector_type(8)));
typedef short bf16x4 __attribute__((ext_vector_type(4)));
typedef float f32x4  __attribute__((ext_vector_type(4)));
typedef const __attribute__((address_space(1))) void gvoid;
typedef __attribute__((address_space(3))) void lvoid;

// fp32 -> bf16 bits, round-to-nearest-even
static __device__ __forceinline__ unsigned short f2bf(float f) {
    unsigned int u = __builtin_bit_cast(unsigned int, f);
    u += 0x7FFFu + ((u >> 16) & 1u);
    return (unsigned short)(u >> 16);
}
// pack two fp32 -> bf16x2 dword (RNE; used in epilogues only)
static __device__ __forceinline__ unsigned int pk2bf(float a, float b) {
    return (unsigned int)f2bf(a) | ((unsigned int)f2bf(b) << 16);
}

// ---------------------------------------------------------------------------
// Fused prep (static-grid version, no counter).
// ---------------------------------------------------------------------------
static __device__ __forceinline__ void transpose_body(
    const float* __restrict__ W, unsigned short* __restrict__ Wt, int N,
    int bx, int by, int tid, float (*T)[65])
{
    const int n0 = bx << 6;
    const int k0 = by << 6;
#pragma unroll
    for (int p = 0; p < 4; ++p) {
        const int idx = p * 256 + tid;
        const int r  = idx >> 4;
        const int c4 = (idx & 15) << 2;
        const float4 v = *(const float4*)&W[(size_t)(k0 + r) * N + n0 + c4];
        T[r][c4 + 0] = v.x; T[r][c4 + 1] = v.y;
        T[r][c4 + 2] = v.z; T[r][c4 + 3] = v.w;
    }
    __syncthreads();
#pragma unroll
    for (int p = 0; p < 4; ++p) {
        const int idx = p * 256 + tid;
        const int r  = idx >> 4;
        const int c4 = (idx & 15) << 2;
        ushort4 o;
        o.x = f2bf(T[c4 + 0][r]); o.y = f2bf(T[c4 + 1][r]);
        o.z = f2bf(T[c4 + 2][r]); o.w = f2bf(T[c4 + 3][r]);
        *(ushort4*)&Wt[(size_t)(n0 + r) * Kdim + k0 + c4] = o;
    }
}

__global__ __launch_bounds__(256) void prep_kernel(
    const float* __restrict__ X, unsigned short* __restrict__ Xb,
    const float* __restrict__ Wqkv, unsigned short* __restrict__ Wqkvt,
    const float* __restrict__ Wproj, unsigned short* __restrict__ Wprojt)
{
    __shared__ float T[64][65];
    const int bid = blockIdx.x;
    const int tid = threadIdx.x;
    if (bid < 1536) {
        const size_t i = ((size_t)bid * 256 + tid) * 8;
        const float4 a = *(const float4*)&X[i];
        const float4 b = *(const float4*)&X[i + 4];
        ushort4 lo, hi;
        lo.x = f2bf(a.x); lo.y = f2bf(a.y); lo.z = f2bf(a.z); lo.w = f2bf(a.w);
        hi.x = f2bf(b.x); hi.y = f2bf(b.y); hi.z = f2bf(b.z); hi.w = f2bf(b.w);
        *(ushort4*)&Xb[i] = lo;
        *(ushort4*)&Xb[i + 4] = hi;
    } else if (bid < 1536 + 432) {
        const int idx = bid - 1536;               // 36 n-tiles x 12 k-tiles
        transpose_body(Wqkv, Wqkvt, N3sz, idx % 36, idx / 36, tid, T);
    } else {
        const int idx = bid - 1968;               // 12 x 12
        transpose_body(Wproj, Wprojt, Dsz, idx % 12, idx / 12, tid, T);
    }
}

// ---------------------------------------------------------------------------
// QKV GEMM (unchanged from R12): 128x128 tile, BK=64, transposed-C MFMA,
// Q/K coalesced row scatter, V written transposed Vt[bh][d][s].
// ---------------------------------------------------------------------------
__global__ __launch_bounds__(256) void qkv_gemm_kernel(
    const unsigned short* __restrict__ A,
    const unsigned short* __restrict__ Bt,
    const float* __restrict__ bias,
    unsigned short* __restrict__ Qo, unsigned short* __restrict__ Ko,
    unsigned short* __restrict__ Vt)
{
    __shared__ unsigned short smem[128 * 136];
    unsigned short* Als = smem;
    unsigned short* Bls = smem + 8192;

    const int tid  = threadIdx.x;
    const int w    = tid >> 6;
    const int lane = tid & 63;
    const int quad = lane >> 4;
    const int t16  = lane & 15;
    const int wm   = w & 1;
    const int wn   = w >> 1;
    const int m0   = blockIdx.y << 7;
    const int n0   = blockIdx.x << 7;

    const int lrow = lane >> 3;
    const int lch  = lane & 7;
    const unsigned short* Ag = A  + (size_t)(m0 + lrow) * Kdim + ((lch ^ lrow) << 3);
    const unsigned short* Bg = Bt + (size_t)(n0 + lrow) * Kdim + ((lch ^ lrow) << 3);

    f32x4 acc[4][4];
#pragma unroll
    for (int mt = 0; mt < 4; ++mt)
#pragma unroll
        for (int nt = 0; nt < 4; ++nt) acc[mt][nt] = (f32x4)(0.f);

    for (int k0 = 0; k0 < Kdim; k0 += 64) {
        __syncthreads();
#pragma unroll
        for (int t = 0; t < 4; ++t) {
            const int i = (w << 2) + t;
            __builtin_amdgcn_global_load_lds(
                (gvoid*)(Ag + (size_t)(i << 3) * Kdim + k0),
                (lvoid*)(Als + (i << 9)), 16, 0, 0);
            __builtin_amdgcn_global_load_lds(
                (gvoid*)(Bg + (size_t)(i << 3) * Kdim + k0),
                (lvoid*)(Bls + (i << 9)), 16, 0, 0);
        }
        __syncthreads();

#pragma unroll
        for (int ks = 0; ks < 2; ++ks) {
            const int sl = (((ks << 2) + quad) ^ (t16 & 7)) << 3;
            bf16x8 af[4], bfr[4];
#pragma unroll
            for (int mt = 0; mt < 4; ++mt)
                af[mt] = *(const bf16x8*)&Als[(((wm << 6) + (mt << 4) + t16) << 6) + sl];
#pragma unroll
            for (int nt = 0; nt < 4; ++nt)
                bfr[nt] = *(const bf16x8*)&Bls[(((wn << 6) + (nt << 4) + t16) << 6) + sl];
#pragma unroll
            for (int mt = 0; mt < 4; ++mt)
#pragma unroll
                for (int nt = 0; nt < 4; ++nt)
                    acc[mt][nt] = __builtin_amdgcn_mfma_f32_16x16x32_bf16(
                        bfr[nt], af[mt], acc[mt][nt], 0, 0, 0);
        }
    }

    __syncthreads();
    {
        const int seg = n0 / Dsz;
        const float sc = (seg == 0) ? 0.18033688f : 1.0f;   // 0.125*log2(e)
#pragma unroll
        for (int nt = 0; nt < 4; ++nt) {
            const int nl = (wn << 6) + (nt << 4) + (quad << 2);
            const float4 bn = *(const float4*)&bias[n0 + nl];
#pragma unroll
            for (int mt = 0; mt < 4; ++mt) {
                const int ml = (wm << 6) + (mt << 4) + t16;
                uint2 o;
                o.x = pk2bf((acc[mt][nt][0] + bn.x) * sc,
                            (acc[mt][nt][1] + bn.y) * sc);
                o.y = pk2bf((acc[mt][nt][2] + bn.z) * sc,
                            (acc[mt][nt][3] + bn.w) * sc);
                *(uint2*)&smem[ml * 136 + nl] = o;
            }
        }
        __syncthreads();

        const int h0 = (n0 % Dsz) >> 6;
        const int bI = m0 >> 11;
        const int s0 = m0 & 2047;
        if (seg < 2) {
            unsigned short* dst0 = (seg == 0) ? Qo : Ko;
            const int chunk = tid & 7;
#pragma unroll
            for (int p = 0; p < 8; ++p) {
                const int unit = p * 32 + (tid >> 3);
                const int ml = unit >> 1;
                const int hc = unit & 1;
                const int s  = s0 + ml;
                const uint4 v = *(const uint4*)&smem[ml * 136 + (hc << 6) + (chunk << 3)];
                *(uint4*)&dst0[(((size_t)bI * Hsz + h0 + hc) * Ssz + s) * DHsz
                               + (chunk << 3)] = v;
            }
        } else {
            const int nrow = tid >> 1;
            const int mh   = tid & 1;
            const int d    = nrow & 63;
            const int hc   = nrow >> 6;
            unsigned short* dst = Vt
                + ((size_t)(bI * Hsz + h0 + hc) * DHsz + d) * Ssz + s0 + (mh << 6);
#pragma unroll
            for (int c = 0; c < 4; ++c) {
                unsigned int dw[8];
#pragma unroll
                for (int k = 0; k < 8; ++k) {
                    const int j = c * 16 + 2 * k;
                    dw[k] = (unsigned int)smem[((mh << 6) + j) * 136 + nrow]
                          | ((unsigned int)smem[((mh << 6) + j + 1) * 136 + nrow] << 16);
                }
                *(uint4*)&dst[c * 16]     = make_uint4(dw[0], dw[1], dw[2], dw[3]);
                *(uint4*)&dst[c * 16 + 8] = make_uint4(dw[4], dw[5], dw[6], dw[7]);
            }
        }
    }
}

// ---------------------------------------------------------------------------
// Proj GEMM: 64x64 tile (unchanged).
// ---------------------------------------------------------------------------
__global__ __launch_bounds__(256) void proj_gemm_kernel(
    const unsigned short* __restrict__ A,
    const unsigned short* __restrict__ Bt,
    const float* __restrict__ bias, float* __restrict__ Out)
{
    __shared__ float smemf[64 * 68];
    unsigned short* Als = (unsigned short*)smemf;
    unsigned short* Bls = Als + 4096;

    const int tid  = threadIdx.x;
    const int w    = tid >> 6;
    const int lane = tid & 63;
    const int quad = lane >> 4;
    const int t16  = lane & 15;
    const int wm   = w & 1;
    const int wn   = w >> 1;
    const int m0   = blockIdx.y << 6;
    const int n0   = blockIdx.x << 6;

    const int lrow = lane >> 3;
    const int lch  = lane & 7;
    const unsigned short* Ag = A  + (size_t)(m0 + lrow) * Kdim + ((lch ^ lrow) << 3);
    const unsigned short* Bg = Bt + (size_t)(n0 + lrow) * Kdim + ((lch ^ lrow) << 3);

    f32x4 acc[2][2];
#pragma unroll
    for (int mt = 0; mt < 2; ++mt)
#pragma unroll
        for (int nt = 0; nt < 2; ++nt) acc[mt][nt] = (f32x4)(0.f);

    for (int k0 = 0; k0 < Kdim; k0 += 64) {
        __syncthreads();
#pragma unroll
        for (int t = 0; t < 2; ++t) {
            const int i = (w << 1) + t;
            __builtin_amdgcn_global_load_lds(
                (gvoid*)(Ag + (size_t)(i << 3) * Kdim + k0),
                (lvoid*)(Als + (i << 9)), 16, 0, 0);
            __builtin_amdgcn_global_load_lds(
                (gvoid*)(Bg + (size_t)(i << 3) * Kdim + k0),
                (lvoid*)(Bls + (i << 9)), 16, 0, 0);
        }
        __syncthreads();

#pragma unroll
        for (int ks = 0; ks < 2; ++ks) {
            const int sl = (((ks << 2) + quad) ^ (t16 & 7)) << 3;
            bf16x8 af[2], bfr[2];
#pragma unroll
            for (int mt = 0; mt < 2; ++mt)
                af[mt] = *(const bf16x8*)&Als[(((wm << 5) + (mt << 4) + t16) << 6) + sl];
#pragma unroll
            for (int nt = 0; nt < 2; ++nt)
                bfr[nt] = *(const bf16x8*)&Bls[(((wn << 5) + (nt << 4) + t16) << 6) + sl];
#pragma unroll
            for (int mt = 0; mt < 2; ++mt)
#pragma unroll
                for (int nt = 0; nt < 2; ++nt)
                    acc[mt][nt] = __builtin_amdgcn_mfma_f32_16x16x32_bf16(
                        bfr[nt], af[mt], acc[mt][nt], 0, 0, 0);
        }
    }

    __syncthreads();
#pragma unroll
    for (int nt = 0; nt < 2; ++nt) {
        const int nl = (wn << 5) + (nt << 4) + (quad << 2);
        const float4 bn = *(const float4*)&bias[n0 + nl];
#pragma unroll
        for (int mt = 0; mt < 2; ++mt) {
            const int ml = (wm << 5) + (mt << 4) + t16;
            float4 o;
            o.x = acc[mt][nt][0] + bn.x;
            o.y = acc[mt][nt][1] + bn.y;
            o.z = acc[mt][nt][2] + bn.z;
            o.w = acc[mt][nt][3] + bn.w;
            *(float4*)&smemf[ml * 68 + nl] = o;
        }
    }
    __syncthreads();
    {
        const int c16 = tid & 15;
#pragma unroll
        for (int p = 0; p < 4; ++p) {
            const int ml = p * 16 + (tid >> 4);
            const float4 v = *(const float4*)&smemf[ml * 68 + (c16 << 2)];
            *(float4*)&Out[(size_t)(m0 + ml) * Dsz + n0 + (c16 << 2)] = v;
        }
    }
}

// ---------------------------------------------------------------------------
// MFMA flash attention v8: REVERTED to static balanced-triple grid (R12 —
// dynamic queue destroyed K/V L2/L3 locality: FETCH 13->52 MB, R13).
// NEW: P packed by TRUNCATION via v_perm_b32 (one instr per pair) instead of
// RNE (~5 ops/pair); l sums the truncated p's (1 AND each) so numerator and
// denominator stay consistent (no bias).
// ---------------------------------------------------------------------------
__global__ __launch_bounds__(256) void attn_mfma_kernel(
    const unsigned short* __restrict__ Q, const unsigned short* __restrict__ K,
    const unsigned short* __restrict__ Vt, unsigned short* __restrict__ Aout)
{
    __shared__ unsigned short Kls[2][64 * 72];   // [buf][kv][d]
    __shared__ unsigned short Vls[2][64 * 72];   // [buf][d][kv]

    const int tid  = threadIdx.x;
    const int w    = tid >> 6;
    const int lane = tid & 63;
    const int quad = lane >> 4;
    const int t16  = lane & 15;

    const int c    = blockIdx.x & 255;
    const int slot = blockIdx.x >> 8;
    const int u    = (slot == 0) ? c : (slot == 1) ? (511 - c) : (512 + c);
    const int qt   = 31 - (u / 24);
    const int bh   = u % 24;
    const int q0   = qt << 6;
    const int bIdx = bh / Hsz;
    const int h    = bh % Hsz;

    const size_t base  = (size_t)bh * Ssz * DHsz;    // K/Q base
    const size_t vbase = (size_t)bh * DHsz * Ssz;    // Vt base

    const int row_a = tid >> 3;          // 0..31 (+32 second item)
    const int ch_a  = tid & 7;           // 16B chunk

    bf16x8 qf[2];
#pragma unroll
    for (int s = 0; s < 2; ++s)
        qf[s] = *(const bf16x8*)&Q[base + (size_t)(q0 + w * 16 + t16) * DHsz
                                   + s * 32 + quad * 8];

    f32x4 O[4];
    float l_ps = 0.f;
#pragma unroll
    for (int dt = 0; dt < 4; ++dt) O[dt] = (f32x4)(0.f);

    // stage tile 0: K rows [kv][d], V rows [d][kv] (both direct b128)
    {
        const unsigned short* Kb = K + base;
        const unsigned short* Vb = Vt + vbase;
        const uint4 k0a = *(const uint4*)&Kb[(size_t)row_a * DHsz + ch_a * 8];
        const uint4 k0b = *(const uint4*)&Kb[(size_t)(row_a + 32) * DHsz + ch_a * 8];
        const uint4 v0a = *(const uint4*)&Vb[(size_t)row_a * Ssz + ch_a * 8];
        const uint4 v0b = *(const uint4*)&Vb[(size_t)(row_a + 32) * Ssz + ch_a * 8];
        *(uint4*)&Kls[0][row_a * 72 + ch_a * 8] = k0a;
        *(uint4*)&Kls[0][(row_a + 32) * 72 + ch_a * 8] = k0b;
        *(uint4*)&Vls[0][row_a * 72 + ch_a * 8] = v0a;
        *(uint4*)&Vls[0][(row_a + 32) * 72 + ch_a * 8] = v0b;
    }
    __syncthreads();

    for (int kt = 0; kt <= qt; ++kt) {
        const int cur = kt & 1;
        const int nxt = cur ^ 1;

        uint4 kr0, kr1, vr0, vr1;
        if (kt < qt) {
            const unsigned short* Kb = K + base + (size_t)((kt + 1) << 6) * DHsz;
            const unsigned short* Vb = Vt + vbase + ((kt + 1) << 6);
            kr0 = *(const uint4*)&Kb[(size_t)row_a * DHsz + ch_a * 8];
            kr1 = *(const uint4*)&Kb[(size_t)(row_a + 32) * DHsz + ch_a * 8];
            vr0 = *(const uint4*)&Vb[(size_t)row_a * Ssz + ch_a * 8];
            vr1 = *(const uint4*)&Vb[(size_t)(row_a + 32) * Ssz + ch_a * 8];
        }

        // S^T = K Q^T
        f32x4 St[4];
#pragma unroll
        for (int kb = 0; kb < 4; ++kb) St[kb] = (f32x4)(0.f);
#pragma unroll
        for (int s = 0; s < 2; ++s)
#pragma unroll
            for (int kb = 0; kb < 4; ++kb) {
                const bf16x8 kf = *(const bf16x8*)&Kls[cur][(kb * 16 + t16) * 72
                                                           + s * 32 + quad * 8];
                St[kb] = __builtin_amdgcn_mfma_f32_16x16x32_bf16(kf, qf[s], St[kb], 0, 0, 0);
            }

        if (kt == qt) {
            const int qrel = w * 16 + t16;
#pragma unroll
            for (int kb = 0; kb < 4; ++kb) {
                const int kvb = kb * 16 + quad * 4;
#pragma unroll
                for (int r = 0; r < 4; ++r)
                    if (kvb + r > qrel) St[kb][r] = -1e30f;
            }
        }

        // no-max softmax; truncation pack via v_perm (1 instr/pair); l sums
        // the truncated values so O/l stays unbiased.
#pragma unroll
        for (int kb = 0; kb < 4; ++kb) {
            const unsigned int u0 = __builtin_bit_cast(unsigned int, exp2f(St[kb][0]));
            const unsigned int u1 = __builtin_bit_cast(unsigned int, exp2f(St[kb][1]));
            const unsigned int u2 = __builtin_bit_cast(unsigned int, exp2f(St[kb][2]));
            const unsigned int u3 = __builtin_bit_cast(unsigned int, exp2f(St[kb][3]));
            const float t0 = __builtin_bit_cast(float, u0 & 0xffff0000u);
            const float t1 = __builtin_bit_cast(float, u1 & 0xffff0000u);
            const float t2 = __builtin_bit_cast(float, u2 & 0xffff0000u);
            const float t3 = __builtin_bit_cast(float, u3 & 0xffff0000u);
            l_ps += (t0 + t1) + (t2 + t3);
            uint2 pk;
            pk.x = __builtin_amdgcn_perm(u1, u0, 0x07060302u);  // {bf16(p1),bf16(p0)}
            pk.y = __builtin_amdgcn_perm(u3, u2, 0x07060302u);
            const bf16x4 pf = __builtin_bit_cast(bf16x4, pk);
#pragma unroll
            for (int dt = 0; dt < 4; ++dt) {
                const bf16x4 vf = *(const bf16x4*)&Vls[cur][(dt * 16 + t16) * 72
                                                            + kb * 16 + quad * 4];
                O[dt] = __builtin_amdgcn_mfma_f32_16x16x16bf16_1k(vf, pf, O[dt], 0, 0, 0);
            }
        }

        if (kt < qt) {
            *(uint4*)&Kls[nxt][row_a * 72 + ch_a * 8] = kr0;
            *(uint4*)&Kls[nxt][(row_a + 32) * 72 + ch_a * 8] = kr1;
            *(uint4*)&Vls[nxt][row_a * 72 + ch_a * 8] = vr0;
            *(uint4*)&Vls[nxt][(row_a + 32) * 72 + ch_a * 8] = vr1;
            __syncthreads();
        }
    }

    l_ps += __shfl_xor(l_ps, 16);
    l_ps += __shfl_xor(l_ps, 32);
    {
        const float inv = 1.0f / l_ps;
        const int q = q0 + w * 16 + t16;
        unsigned short* dst = Aout + ((size_t)bIdx * Ssz + q) * Dsz + (h << 6);
#pragma unroll
        for (int dt = 0; dt < 4; ++dt) {
            uint2 o;
            o.x = pk2bf(O[dt][0] * inv, O[dt][1] * inv);
            o.y = pk2bf(O[dt][2] * inv, O[dt][3] * inv);
            *(uint2*)&dst[dt * 16 + quad * 4] = o;
        }
    }
}

// ---------------------------------------------------------------------------
extern "C" void kernel_launch(void* const* d_in, const int* in_sizes, int n_in,
                              void* d_out, int out_size, void* d_ws, size_t ws_size,
                              hipStream_t stream) {
    const float* x        = (const float*)d_in[0];
    const float* c_attn_w = (const float*)d_in[2];
    const float* c_attn_b = (const float*)d_in[3];
    const float* c_proj_w = (const float*)d_in[4];
    const float* c_proj_b = (const float*)d_in[5];
    float* out = (float*)d_out;

    const size_t T = (size_t)Msz * Dsz;           // 3145728
    unsigned short* xb     = (unsigned short*)d_ws;
    unsigned short* Wqkvt  = xb + T;
    unsigned short* Wprojt = Wqkvt + (size_t)N3sz * Kdim;
    unsigned short* Qw     = Wprojt + (size_t)Dsz * Kdim;
    unsigned short* Kw     = Qw + T;
    unsigned short* Vw     = Kw + T;               // Vt layout [bh][d][s]
    unsigned short* Ab     = Vw + T;

    prep_kernel<<<2112, 256, 0, stream>>>(x, xb, c_attn_w, Wqkvt, c_proj_w, Wprojt);
    qkv_gemm_kernel<<<dim3(N3sz / 128, Msz / 128), 256, 0, stream>>>(
        xb, Wqkvt, c_attn_b, Qw, Kw, Vw);
    attn_mfma_kernel<<<32 * 24, 256, 0, stream>>>(Qw, Kw, Vw, Ab);
    proj_gemm_kernel<<<dim3(Dsz / 64, Msz / 64), 256, 0, stream>>>(
        Ab, Wprojt, c_proj_b, out);
}